// Round 1
// 270.160 us; speedup vs baseline: 1.1722x; 1.1722x over previous
//
#include <hip/hip_runtime.h>
#include <hip/hip_bf16.h>
#include <math.h>

// Problem constants (fixed by reference)
#define NN 100000   // nodes
#define FF 128      // features
#define DD 16       // degree
#define KK 8        // hashers
#define HH 256      // hash dim
#define OO 256      // out dim
#define KH 2048     // K*H
// Main GEMM: C[NN,256] = A[NN,256](bf16) @ Bw[256,256](bf16), K-dim = 2F = 256
// A cols 0..127 = mean(neigh) features, 128..255 = self features.
// Bw rows 0..127 = An = R_flat @ Wn^T ; rows 128..255 = As = R_flat @ Ws^T.
// R2: A is never materialized — gather+mean fused into the GEMM's A-staging.

using frag_t  = __attribute__((ext_vector_type(8))) short;   // 8 bf16 = 4 VGPR (MFMA A/B frag)
using f32x4   = __attribute__((ext_vector_type(4))) float;   // MFMA C/D frag
using ushort8 = __attribute__((ext_vector_type(8))) unsigned short;

static __device__ __forceinline__ float bf2f(unsigned int u16) {
    union { unsigned int i; float f; } v; v.i = u16 << 16; return v.f;
}
static __device__ __forceinline__ unsigned short f2bf(float f) {
    union { float f; unsigned int i; } v; v.f = f;
    unsigned int x = v.i;
    x += 0x7fffu + ((x >> 16) & 1u);   // round-to-nearest-even
    return (unsigned short)(x >> 16);
}

// ---------------- Kernel 1: cast x (fp32) -> xb (bf16), 8 elem/thread ----------------
__global__ __launch_bounds__(256) void k_cast(const float* __restrict__ x,
                                              unsigned short* __restrict__ xb) {
    int t = blockIdx.x * 256 + threadIdx.x;      // 1.6M threads, 8 floats each
    const float4* xv = (const float4*)x;
    float4 a = xv[2 * t], b = xv[2 * t + 1];
    ushort8 o;
    o[0] = f2bf(a.x); o[1] = f2bf(a.y); o[2] = f2bf(a.z); o[3] = f2bf(a.w);
    o[4] = f2bf(b.x); o[5] = f2bf(b.y); o[6] = f2bf(b.z); o[7] = f2bf(b.w);
    *(ushort8*)(xb + (size_t)t * 8) = o;
}

// ------- Kernel 2: weight precompute, fp32 tiled GEMM, K-split into 8 partials -------
// P[z][f2][o] += sum_{j in z-chunk} R_flat[f2&127, j] * W[o, j]
// grid (4 f2-tiles of 64, 4 o-tiles of 64, 8 k-chunks of 256). 256 thr, 4x4 microtile.
__global__ __launch_bounds__(256) void k_wgemm(const float* __restrict__ R,
                                               const float* __restrict__ Ws,
                                               const float* __restrict__ Wn,
                                               float* __restrict__ P) {
    __shared__ float a_s[16][68];
    __shared__ float w_s[16][68];
    int bx = blockIdx.x, by = blockIdx.y, bz = blockIdx.z;
    const float* W = (bx < 2) ? Wn : Ws;          // f2 0..127 -> Wn (neigh), else Ws (self)
    int fbase = (bx & 1) * 64;
    int t = threadIdx.x;
    int tx = t & 15, ty = t >> 4;
    int lf = t >> 2;              // 0..63: ff (R row) / oo (W row)
    int j4 = (t & 3) * 4;         // 0,4,8,12
    float acc[4][4] = {};
    // j = bz*256 + ks*16 + jj ; hasher k = bz exactly (chunk aligns with H=256)
    const float* Rb = R + (size_t)bz * (FF * HH) + (size_t)(fbase + lf) * HH;
    const float* Wb = W + (size_t)(by * 64 + lf) * KH + (size_t)bz * 256;
    for (int ks = 0; ks < 16; ++ks) {
        float4 av = *(const float4*)(Rb + ks * 16 + j4);
        float4 wv = *(const float4*)(Wb + ks * 16 + j4);
        __syncthreads();
        a_s[j4 + 0][lf] = av.x; a_s[j4 + 1][lf] = av.y;
        a_s[j4 + 2][lf] = av.z; a_s[j4 + 3][lf] = av.w;
        w_s[j4 + 0][lf] = wv.x; w_s[j4 + 1][lf] = wv.y;
        w_s[j4 + 2][lf] = wv.z; w_s[j4 + 3][lf] = wv.w;
        __syncthreads();
#pragma unroll
        for (int jj = 0; jj < 16; ++jj) {
            float ar[4], wr[4];
#pragma unroll
            for (int i = 0; i < 4; ++i) ar[i] = a_s[jj][ty * 4 + i];
#pragma unroll
            for (int j = 0; j < 4; ++j) wr[j] = w_s[jj][tx * 4 + j];
#pragma unroll
            for (int i = 0; i < 4; ++i)
#pragma unroll
                for (int j = 0; j < 4; ++j) acc[i][j] += ar[i] * wr[j];
        }
    }
    float* Pb = P + (size_t)bz * 65536 + (size_t)(bx * 64) * 256 + by * 64;
#pragma unroll
    for (int i = 0; i < 4; ++i) {
        float4 v = make_float4(acc[i][0], acc[i][1], acc[i][2], acc[i][3]);
        *(float4*)(Pb + (size_t)(ty * 4 + i) * 256 + tx * 4) = v;
    }
}

// ---- Kernel 3: combine 8 partials, transpose to Bbf[o][f2] (bf16) for GEMM B-frags ----
__global__ __launch_bounds__(256) void k_comb(const float* __restrict__ P,
                                              unsigned short* __restrict__ Bbf) {
    __shared__ float tsh[64][65];
    int bf = blockIdx.x, bo = blockIdx.y;    // 4x4 tiles of 64
    int t = threadIdx.x;
    for (int e = t; e < 4096; e += 256) {
        int r = e >> 6, c = e & 63;          // r = f2-local, c = o-local (coalesced reads)
        float s = 0.f;
#pragma unroll
        for (int z = 0; z < 8; ++z)
            s += P[(size_t)z * 65536 + (size_t)(bf * 64 + r) * 256 + bo * 64 + c];
        tsh[r][c] = s;
    }
    __syncthreads();
    for (int e = t; e < 4096; e += 256) {
        int r = e >> 6, c = e & 63;          // r = o-local, c = f2-local (coalesced writes)
        Bbf[(size_t)(bo * 64 + r) * 256 + bf * 64 + c] = f2bf(tsh[c][r]);
    }
}

// --------- Kernel 4 (fused): gather-mean -> LDS A-tile -> MFMA GEMM + bias + ELU ---------
// BM=64 rows x BN=256 cols per block, 512 threads = 8 waves (each wave: 64x32, 4x2 frags).
// LDS: Als[64][264] bf16 (33.8 KB, A rows, +8 pad keeps frag reads ~2-way) +
//      Bls[256][72] bf16 (36.9 KB, one K-tile of 64). 70.7 KB -> 2 blocks/CU (50% occ):
//      gather phase of one block overlaps MFMA/store phase of the other.
__global__ __launch_bounds__(512, 4) void k_fused(const unsigned short* __restrict__ xb,
                                                  const int* __restrict__ nbr,
                                                  const unsigned short* __restrict__ Bw,
                                                  const float* __restrict__ bias,
                                                  float* __restrict__ C) {
    __shared__ unsigned short Als[64][264];   // row stride 528 B = 33x16B (16B aligned)
    __shared__ unsigned short Bls[256][72];   // row stride 144 B (same as old k_gemm)
    int m0 = blockIdx.x * 64;
    int t = threadIdx.x;
    int lane = t & 63, wv = t >> 6;           // 8 waves
    int l15 = lane & 15, quad = lane >> 4;

    // ---- issue B kt=0 loads early (B is 128 KB, L2-hot after first blocks)
    ushort8 bst[4];
    int brow[4], bcol[4];
#pragma unroll
    for (int s = 0; s < 4; ++s) {
        int c = s * 512 + t;                  // 2048 chunks of 8 bf16 = [256][64] tile
        brow[s] = c >> 3; bcol[s] = (c & 7) * 8;
        bst[s] = *(const ushort8*)(Bw + (size_t)brow[s] * 256 + bcol[s]);
    }

    // ---- gather phase: 8 A-rows per wave; mean of 16 nbr rows (256 B each, L3-resident)
    const int rbase = wv * 8;
#pragma unroll 2
    for (int r = 0; r < 8; ++r) {
        int row = rbase + r;
        int node = m0 + row; if (node >= NN) node = NN - 1;   // tail rows: gather row N-1
        node = __builtin_amdgcn_readfirstlane(node);          // wave-uniform -> s_loads for nbr
        const int* nb = nbr + (size_t)node * 16;
        unsigned int self = *(const unsigned int*)(xb + (size_t)node * 128 + lane * 2);
        float s0 = 0.f, s1 = 0.f;
#pragma unroll
        for (int d = 0; d < 16; ++d) {
            int idx = nb[d];
            unsigned int v = *(const unsigned int*)(xb + (size_t)idx * 128 + lane * 2);
            s0 += bf2f(v & 0xffffu);
            s1 += bf2f(v >> 16);
        }
        s0 *= 0.0625f; s1 *= 0.0625f;
        *(unsigned int*)&Als[row][lane * 2] =
            (unsigned int)f2bf(s0) | ((unsigned int)f2bf(s1) << 16);
        *(unsigned int*)&Als[row][128 + lane * 2] = self;
    }
    // write staged B kt=0
#pragma unroll
    for (int s = 0; s < 4; ++s) *(ushort8*)&Bls[brow[s]][bcol[s]] = bst[s];
    __syncthreads();

    f32x4 acc[4][2] = {};
#pragma unroll 1
    for (int kt = 0; kt < 4; ++kt) {
        // prefetch next B K-tile into regs while computing current (latency hidden)
        if (kt < 3) {
#pragma unroll
            for (int s = 0; s < 4; ++s)
                bst[s] = *(const ushort8*)(Bw + (size_t)brow[s] * 256 + (kt + 1) * 64 + bcol[s]);
        }
#pragma unroll
        for (int k2 = 0; k2 < 2; ++k2) {
            frag_t af[4], bfr[2];
#pragma unroll
            for (int i = 0; i < 4; ++i)
                af[i] = *(const frag_t*)&Als[i * 16 + l15][kt * 64 + k2 * 32 + quad * 8];
#pragma unroll
            for (int j = 0; j < 2; ++j)
                bfr[j] = *(const frag_t*)&Bls[wv * 32 + j * 16 + l15][k2 * 32 + quad * 8];
#pragma unroll
            for (int i = 0; i < 4; ++i)
#pragma unroll
                for (int j = 0; j < 2; ++j)
                    acc[i][j] = __builtin_amdgcn_mfma_f32_16x16x32_bf16(af[i], bfr[j], acc[i][j], 0, 0, 0);
        }
        __syncthreads();
        if (kt < 3) {
#pragma unroll
            for (int s = 0; s < 4; ++s) *(ushort8*)&Bls[brow[s]][bcol[s]] = bst[s];
            __syncthreads();
        }
    }
    // epilogue: C/D layout col=lane&15, row=quad*4+reg (m89-verified, same as old k_gemm)
#pragma unroll
    for (int j = 0; j < 2; ++j) {
        int col = wv * 32 + j * 16 + l15;
        float bv = bias[col];
#pragma unroll
        for (int i = 0; i < 4; ++i) {
            int row0 = m0 + i * 16 + quad * 4;
#pragma unroll
            for (int r = 0; r < 4; ++r) {
                int row = row0 + r;
                if (row < NN) {
                    float v = acc[i][j][r] + bv;
                    C[(size_t)row * 256 + col] = (v > 0.f) ? v : expm1f(v);  // ELU(alpha=1)
                }
            }
        }
    }
}

// ---------------------------------- launcher ----------------------------------
extern "C" void kernel_launch(void* const* d_in, const int* in_sizes, int n_in,
                              void* d_out, int out_size, void* d_ws, size_t ws_size,
                              hipStream_t stream) {
    const float* x    = (const float*)d_in[0];
    const int*   nbr  = (const int*)d_in[1];
    const float* R    = (const float*)d_in[2];
    const float* Ws   = (const float*)d_in[3];
    const float* Wn   = (const float*)d_in[4];
    const float* bias = (const float*)d_in[5];
    float* out = (float*)d_out;

    // workspace layout (all 16B-aligned): total ~27.8 MB (Abf intermediate eliminated)
    char* ws = (char*)d_ws;
    unsigned short* xb  = (unsigned short*)(ws);                       // 25,600,000 B
    float*          P   = (float*)(ws + 25600000);                     //  2,097,152 B
    unsigned short* Bbf = (unsigned short*)(ws + 25600000 + 2097152);  //    131,072 B

    hipLaunchKernelGGL(k_cast,   dim3(6250),    dim3(256), 0, stream, x, xb);
    hipLaunchKernelGGL(k_wgemm,  dim3(4, 4, 8), dim3(256), 0, stream, R, Ws, Wn, P);
    hipLaunchKernelGGL(k_comb,   dim3(4, 4),    dim3(256), 0, stream, P, Bbf);
    hipLaunchKernelGGL(k_fused,  dim3(1563),    dim3(512), 0, stream, xb, nbr, Bbf, bias, out);
}

// Round 3
// 256.652 us; speedup vs baseline: 1.2339x; 1.0526x over previous
//
#include <hip/hip_runtime.h>
#include <hip/hip_bf16.h>
#include <math.h>

// Problem constants (fixed by reference)
#define NN 100000   // nodes
#define FF 128      // features
#define DD 16       // degree
#define KK 8        // hashers
#define HH 256      // hash dim
#define OO 256      // out dim
#define KH 2048     // K*H
// C[NN,256] = A[NN,256](bf16) @ Bw[256,256](bf16), K = 2F = 256.
// A cols 0..127 = mean(neigh), 128..255 = self. Bw rows: 0..127 Wn-part, 128..255 Ws-part.
// R3 (= R2 resubmit): gather via 4-rows-per-dwordx4 + ds_bpermute idx broadcast, no Bls
//   (B-frags straight from L2), zero-barrier K-loop, LDS-staged full-line epilogue.
//   Change vs R2: __launch_bounds__(512,4) — R2's (512,6) capped VGPR at ~85 and risked
//   scratch spills in the gather (8 uint4 in flight); container failure was infra-level.

using frag_t  = __attribute__((ext_vector_type(8))) short;   // 8 bf16 = 4 VGPR (MFMA A/B frag)
using f32x4   = __attribute__((ext_vector_type(4))) float;   // MFMA C/D frag
using ushort8 = __attribute__((ext_vector_type(8))) unsigned short;

static __device__ __forceinline__ float bf2f(unsigned int u16) {
    union { unsigned int i; float f; } v; v.i = u16 << 16; return v.f;
}
static __device__ __forceinline__ float blo(unsigned int u) {   // low bf16 of packed pair
    union { unsigned int i; float f; } v; v.i = u << 16; return v.f;
}
static __device__ __forceinline__ float bhi(unsigned int u) {   // high bf16 of packed pair
    union { unsigned int i; float f; } v; v.i = u & 0xffff0000u; return v.f;
}
static __device__ __forceinline__ unsigned short f2bf(float f) {
    union { float f; unsigned int i; } v; v.f = f;
    unsigned int x = v.i;
    x += 0x7fffu + ((x >> 16) & 1u);   // round-to-nearest-even
    return (unsigned short)(x >> 16);
}

// ---------------- Kernel 1: cast x (fp32) -> xb (bf16), 8 elem/thread ----------------
__global__ __launch_bounds__(256) void k_cast(const float* __restrict__ x,
                                              unsigned short* __restrict__ xb) {
    int t = blockIdx.x * 256 + threadIdx.x;      // 1.6M threads, 8 floats each
    const float4* xv = (const float4*)x;
    float4 a = xv[2 * t], b = xv[2 * t + 1];
    ushort8 o;
    o[0] = f2bf(a.x); o[1] = f2bf(a.y); o[2] = f2bf(a.z); o[3] = f2bf(a.w);
    o[4] = f2bf(b.x); o[5] = f2bf(b.y); o[6] = f2bf(b.z); o[7] = f2bf(b.w);
    *(ushort8*)(xb + (size_t)t * 8) = o;
}

// ------- Kernel 2: weight precompute, fp32 tiled GEMM, K-split into 8 partials -------
__global__ __launch_bounds__(256) void k_wgemm(const float* __restrict__ R,
                                               const float* __restrict__ Ws,
                                               const float* __restrict__ Wn,
                                               float* __restrict__ P) {
    __shared__ float a_s[16][68];
    __shared__ float w_s[16][68];
    int bx = blockIdx.x, by = blockIdx.y, bz = blockIdx.z;
    const float* W = (bx < 2) ? Wn : Ws;          // f2 0..127 -> Wn (neigh), else Ws (self)
    int fbase = (bx & 1) * 64;
    int t = threadIdx.x;
    int tx = t & 15, ty = t >> 4;
    int lf = t >> 2;              // 0..63: ff (R row) / oo (W row)
    int j4 = (t & 3) * 4;         // 0,4,8,12
    float acc[4][4] = {};
    const float* Rb = R + (size_t)bz * (FF * HH) + (size_t)(fbase + lf) * HH;
    const float* Wb = W + (size_t)(by * 64 + lf) * KH + (size_t)bz * 256;
    for (int ks = 0; ks < 16; ++ks) {
        float4 av = *(const float4*)(Rb + ks * 16 + j4);
        float4 wv = *(const float4*)(Wb + ks * 16 + j4);
        __syncthreads();
        a_s[j4 + 0][lf] = av.x; a_s[j4 + 1][lf] = av.y;
        a_s[j4 + 2][lf] = av.z; a_s[j4 + 3][lf] = av.w;
        w_s[j4 + 0][lf] = wv.x; w_s[j4 + 1][lf] = wv.y;
        w_s[j4 + 2][lf] = wv.z; w_s[j4 + 3][lf] = wv.w;
        __syncthreads();
#pragma unroll
        for (int jj = 0; jj < 16; ++jj) {
            float ar[4], wr[4];
#pragma unroll
            for (int i = 0; i < 4; ++i) ar[i] = a_s[jj][ty * 4 + i];
#pragma unroll
            for (int j = 0; j < 4; ++j) wr[j] = w_s[jj][tx * 4 + j];
#pragma unroll
            for (int i = 0; i < 4; ++i)
#pragma unroll
                for (int j = 0; j < 4; ++j) acc[i][j] += ar[i] * wr[j];
        }
    }
    float* Pb = P + (size_t)bz * 65536 + (size_t)(bx * 64) * 256 + by * 64;
#pragma unroll
    for (int i = 0; i < 4; ++i) {
        float4 v = make_float4(acc[i][0], acc[i][1], acc[i][2], acc[i][3]);
        *(float4*)(Pb + (size_t)(ty * 4 + i) * 256 + tx * 4) = v;
    }
}

// ---- Kernel 3: combine 8 partials, transpose to Bbf[o][f2] (bf16) for GEMM B-frags ----
__global__ __launch_bounds__(256) void k_comb(const float* __restrict__ P,
                                              unsigned short* __restrict__ Bbf) {
    __shared__ float tsh[64][65];
    int bf = blockIdx.x, bo = blockIdx.y;    // 4x4 tiles of 64
    int t = threadIdx.x;
    for (int e = t; e < 4096; e += 256) {
        int r = e >> 6, c = e & 63;          // r = f2-local, c = o-local (coalesced reads)
        float s = 0.f;
#pragma unroll
        for (int z = 0; z < 8; ++z)
            s += P[(size_t)z * 65536 + (size_t)(bf * 64 + r) * 256 + bo * 64 + c];
        tsh[r][c] = s;
    }
    __syncthreads();
    for (int e = t; e < 4096; e += 256) {
        int r = e >> 6, c = e & 63;          // r = o-local, c = f2-local (coalesced writes)
        Bbf[(size_t)(bo * 64 + r) * 256 + bf * 64 + c] = f2bf(tsh[c][r]);
    }
}

// --------- Kernel 4 (fused): gather-mean -> LDS A-tile -> MFMA GEMM + bias + ELU ---------
// BM=64 x BN=256, 512 threads = 8 waves, wave tile 64x32 (acc 4x2 frags).
// Gather: lane=(r4,l16) -> one dwordx4 gathers 4 rows x 16B = 1KB/instr; nbr idx
//   broadcast per-d via ds_bpermute from per-lane-preloaded indices.
// LDS: Als[64][264] bf16 only (33.8 KB); B-frags read straight from global (128 KB,
//   L2-hot); K-loop has NO barriers (Als read-only after one syncthreads).
// Epilogue: acc -> LDS float[32][260] (reuse Als) -> full-line float4 stores, 2 passes.
__global__ __launch_bounds__(512, 4) void k_fused(const unsigned short* __restrict__ xb,
                                                  const int* __restrict__ nbr,
                                                  const unsigned short* __restrict__ Bw,
                                                  const float* __restrict__ bias,
                                                  float* __restrict__ C) {
    __shared__ __align__(16) char smraw[64 * 264 * 2];   // 33792 B, dual-purpose
    unsigned short (*Als)[264] = (unsigned short (*)[264])smraw;
    float* Fls = (float*)smraw;                          // [32][260] floats (33280 B)
    const int FLS_W = 260;

    int m0 = blockIdx.x * 64;
    int t = threadIdx.x;
    int lane = t & 63, wv = t >> 6;           // 8 waves
    int l15 = lane & 15, quad = lane >> 4;
    int l16 = lane & 15, r4 = lane >> 4;      // gather mapping: 4 rows x 16 feature-lanes
    int selbase = (lane & 48) << 2;           // bpermute selector base (group start lane *4)

    // ---- gather phase: 2 groups of 4 rows; per group 16 dwordx4 gathers + self + pack
#pragma unroll
    for (int g = 0; g < 2; ++g) {
        int row = wv * 8 + g * 4 + r4;                    // block-local row 0..63
        int node = m0 + row; if (node >= NN) node = NN - 1;
        int myidx = nbr[(size_t)node * 16 + l16];         // lane holds nbr #l16 of its row
        uint4 selfv = *(const uint4*)(xb + (size_t)node * 128 + l16 * 8);
        float s[8] = {0.f, 0.f, 0.f, 0.f, 0.f, 0.f, 0.f, 0.f};
#pragma unroll
        for (int h = 0; h < 2; ++h) {                     // 2 batches of 8 loads in flight
            uint4 gv[8];
#pragma unroll
            for (int d = 0; d < 8; ++d) {
                int bi = __builtin_amdgcn_ds_bpermute(selbase + ((h * 8 + d) << 2), myidx);
                gv[d] = *(const uint4*)(xb + (size_t)bi * 128 + l16 * 8);
            }
#pragma unroll
            for (int d = 0; d < 8; ++d) {
                s[0] += blo(gv[d].x); s[1] += bhi(gv[d].x);
                s[2] += blo(gv[d].y); s[3] += bhi(gv[d].y);
                s[4] += blo(gv[d].z); s[5] += bhi(gv[d].z);
                s[6] += blo(gv[d].w); s[7] += bhi(gv[d].w);
            }
        }
        ushort8 o;
#pragma unroll
        for (int k = 0; k < 8; ++k) o[k] = f2bf(s[k] * 0.0625f);
        *(ushort8*)&Als[row][l16 * 8] = o;                // mean features 0..127
        *(uint4*)&Als[row][128 + l16 * 8] = selfv;        // self features 128..255
    }
    __syncthreads();

    // ---- K-loop: barrier-free; B-frags from global (L2-hot 128 KB)
    f32x4 acc[4][2] = {};
#pragma unroll 1
    for (int kt = 0; kt < 4; ++kt) {
#pragma unroll
        for (int k2 = 0; k2 < 2; ++k2) {
            frag_t bfr[2], af[4];
#pragma unroll
            for (int j = 0; j < 2; ++j)
                bfr[j] = *(const frag_t*)(Bw + (size_t)(wv * 32 + j * 16 + l15) * 256
                                             + kt * 64 + k2 * 32 + quad * 8);
#pragma unroll
            for (int i = 0; i < 4; ++i)
                af[i] = *(const frag_t*)&Als[i * 16 + l15][kt * 64 + k2 * 32 + quad * 8];
#pragma unroll
            for (int i = 0; i < 4; ++i)
#pragma unroll
                for (int j = 0; j < 2; ++j)
                    acc[i][j] = __builtin_amdgcn_mfma_f32_16x16x32_bf16(af[i], bfr[j], acc[i][j], 0, 0, 0);
        }
    }

    // ---- epilogue: bias+ELU in-reg, stage 32-row halves in LDS, full-line float4 stores
    float bv[2];
#pragma unroll
    for (int j = 0; j < 2; ++j) bv[j] = bias[wv * 32 + j * 16 + l15];
#pragma unroll
    for (int p = 0; p < 2; ++p) {
        __syncthreads();     // p=0: Als frag reads done; p=1: prev pass reads done
#pragma unroll
        for (int ii = 0; ii < 2; ++ii) {
            int i = p * 2 + ii;
#pragma unroll
            for (int j = 0; j < 2; ++j) {
                int col = wv * 32 + j * 16 + l15;
#pragma unroll
                for (int r = 0; r < 4; ++r) {
                    int lr = ii * 16 + quad * 4 + r;      // local row within 32-row pass
                    float v = acc[i][j][r] + bv[j];
                    v = (v > 0.f) ? v : expm1f(v);        // ELU(alpha=1)
                    Fls[lr * FLS_W + col] = v;
                }
            }
        }
        __syncthreads();
#pragma unroll
        for (int q = 0; q < 4; ++q) {                     // 32 rows x 256 cols, float4
            int f4 = q * 512 + t;
            int lr = f4 >> 6, c4 = f4 & 63;
            int grow = m0 + p * 32 + lr;
            if (grow < NN)
                *(float4*)(C + (size_t)grow * 256 + c4 * 4) = *(const float4*)&Fls[lr * FLS_W + c4 * 4];
        }
    }
}

// ---------------------------------- launcher ----------------------------------
extern "C" void kernel_launch(void* const* d_in, const int* in_sizes, int n_in,
                              void* d_out, int out_size, void* d_ws, size_t ws_size,
                              hipStream_t stream) {
    const float* x    = (const float*)d_in[0];
    const int*   nbr  = (const int*)d_in[1];
    const float* R    = (const float*)d_in[2];
    const float* Ws   = (const float*)d_in[3];
    const float* Wn   = (const float*)d_in[4];
    const float* bias = (const float*)d_in[5];
    float* out = (float*)d_out;

    // workspace layout (all 16B-aligned): ~27.8 MB
    char* ws = (char*)d_ws;
    unsigned short* xb  = (unsigned short*)(ws);                       // 25,600,000 B
    float*          P   = (float*)(ws + 25600000);                     //  2,097,152 B
    unsigned short* Bbf = (unsigned short*)(ws + 25600000 + 2097152);  //    131,072 B

    hipLaunchKernelGGL(k_cast,   dim3(6250),    dim3(256), 0, stream, x, xb);
    hipLaunchKernelGGL(k_wgemm,  dim3(4, 4, 8), dim3(256), 0, stream, R, Ws, Wn, P);
    hipLaunchKernelGGL(k_comb,   dim3(4, 4),    dim3(256), 0, stream, P, Bbf);
    hipLaunchKernelGGL(k_fused,  dim3(1563),    dim3(512), 0, stream, xb, nbr, Bbf, bias, out);
}